// Round 3
// baseline (2836.696 us; speedup 1.0000x reference)
//
#include <hip/hip_runtime.h>

typedef _Float16 f16;
typedef _Float16 f16x8 __attribute__((ext_vector_type(8)));
typedef float    f32x4 __attribute__((ext_vector_type(4)));

constexpr int TT = 512;   // timesteps
constexpr int FF = 64;    // input features
constexpr int H1 = 128;   // layer-1 hidden (512 gate cols)
constexpr int H2 = 64;    // layer-2 hidden (256 gate cols)
constexpr int D1 = 25;    // dense-1 width
constexpr int S1 = 136;   // h1 LDS row stride (f16): keeps b128 reads 16B-aligned + banks even
constexpr int S2 = 136;   // h2 LDS row stride

__device__ __forceinline__ float sigm(float z) { return 1.f / (1.f + __expf(-z)); }

__device__ __forceinline__ f32x4 mfma16(f16x8 a, f16x8 b, f32x4 c) {
    return __builtin_amdgcn_mfma_f32_16x16x32_f16(a, b, c, 0, 0, 0);
}

// 32 blocks x 768 threads (12 waves). Waves 0-7: layer-1 step t (wave w owns
// gate cols 128g+16w+lid, g=0..3). Waves 8-11: layer-2 step t-1 (wave 8+j owns
// gate cols 64g+16j+lid). Ping-pong h1/h2 buffers => ONE barrier per step.
// x prefetched per-wave from global into A-fragments one step ahead.
__global__ __launch_bounds__(768, 3)
void lstm_pipe(const float* __restrict__ x,  const float* __restrict__ W1,
               const float* __restrict__ U1, const float* __restrict__ b1,
               const float* __restrict__ W2, const float* __restrict__ U2,
               const float* __restrict__ b2, const float* __restrict__ Wd1,
               const float* __restrict__ bd1,const float* __restrict__ Wd2,
               const float* __restrict__ bd2, float* __restrict__ out)
{
    const int tid  = threadIdx.x;
    const int w    = tid >> 6;      // wave 0..11
    const int lane = tid & 63;
    const int quad = lane >> 4;     // 0..3
    const int lid  = lane & 15;     // 0..15
    const int b0   = blockIdx.x * 16;

    __shared__ __align__(16) f16 h1b[2][16][S1];
    __shared__ __align__(16) f16 h2b[2][16][S2];
    __shared__ float h2f[16][H2];
    __shared__ float dsh[16][D1];

    // zero the ping-pong state buffers
    for (int i = tid; i < 2 * 16 * S1 / 2; i += 768) ((unsigned*)h1b)[i] = 0u;
    for (int i = tid; i < 2 * 16 * S2 / 2; i += 768) ((unsigned*)h2b)[i] = 0u;

    // ---------------- per-role weight fragments (B-layout: n=lid, k=quad*8+e) ----------------
    f16x8 wx[4][2];   // L1 x-part   (only valid for w<8)
    f16x8 wh[4][4];   // L1 h-part
    f16x8 v2w[4][4];  // L2 h1-part  (only valid for w>=8)
    f16x8 v2u[4][2];  // L2 h2-part
    float bias[4];
    float cs[4] = {0.f, 0.f, 0.f, 0.f};   // cell state, rows quad*4+r
    f16x8 xf[2];                           // current x A-fragment (L1 waves)

    if (w < 8) {
#pragma unroll
        for (int g = 0; g < 4; ++g) {
            const int n = 128 * g + 16 * w + lid;
            bias[g] = b1[n];
#pragma unroll
            for (int c = 0; c < 2; ++c) {
                f16x8 f;
#pragma unroll
                for (int e = 0; e < 8; ++e)
                    f[e] = (f16)W1[(32 * c + quad * 8 + e) * 512 + n];
                wx[g][c] = f;
            }
#pragma unroll
            for (int c = 0; c < 4; ++c) {
                f16x8 f;
#pragma unroll
                for (int e = 0; e < 8; ++e)
                    f[e] = (f16)U1[(32 * c + quad * 8 + e) * 512 + n];
                wh[g][c] = f;
            }
        }
        // x A-fragment for t=0: A[m=lid][k=quad*8+e], k in [0,64)
        const float* xr = x + (size_t)(b0 + lid) * TT * FF + quad * 8;
        float4 p0 = *(const float4*)(xr);
        float4 p1 = *(const float4*)(xr + 4);
        float4 p2 = *(const float4*)(xr + 32);
        float4 p3 = *(const float4*)(xr + 36);
        f16x8 f0, f1;
        f0[0]=(f16)p0.x; f0[1]=(f16)p0.y; f0[2]=(f16)p0.z; f0[3]=(f16)p0.w;
        f0[4]=(f16)p1.x; f0[5]=(f16)p1.y; f0[6]=(f16)p1.z; f0[7]=(f16)p1.w;
        f1[0]=(f16)p2.x; f1[1]=(f16)p2.y; f1[2]=(f16)p2.z; f1[3]=(f16)p2.w;
        f1[4]=(f16)p3.x; f1[5]=(f16)p3.y; f1[6]=(f16)p3.z; f1[7]=(f16)p3.w;
        xf[0] = f0; xf[1] = f1;
    } else {
        const int j = w - 8;
#pragma unroll
        for (int g = 0; g < 4; ++g) {
            const int n = 64 * g + 16 * j + lid;
            bias[g] = b2[n];
#pragma unroll
            for (int c = 0; c < 4; ++c) {
                f16x8 f;
#pragma unroll
                for (int e = 0; e < 8; ++e)
                    f[e] = (f16)W2[(32 * c + quad * 8 + e) * 256 + n];
                v2w[g][c] = f;
            }
#pragma unroll
            for (int c = 0; c < 2; ++c) {
                f16x8 f;
#pragma unroll
                for (int e = 0; e < 8; ++e)
                    f[e] = (f16)U2[(32 * c + quad * 8 + e) * 256 + n];
                v2u[g][c] = f;
            }
        }
    }
    __syncthreads();

    // ---------------- main pipelined recurrence: ONE barrier per iteration ----------------
    for (int i = 0; i <= TT; ++i) {
        if (w < 8) {
            if (i < TT) {
                const int pr = (i + 1) & 1;   // h1[i-1]
                const int pw = i & 1;         // h1[i]
                f16x8 ah0 = *(const f16x8*)&h1b[pr][lid][quad * 8];
                f16x8 ah1 = *(const f16x8*)&h1b[pr][lid][32 + quad * 8];
                f16x8 ah2 = *(const f16x8*)&h1b[pr][lid][64 + quad * 8];
                f16x8 ah3 = *(const f16x8*)&h1b[pr][lid][96 + quad * 8];

                // prefetch x[i+1]
                float4 p0, p1, p2, p3;
                const bool hx = (i + 1 < TT);
                if (hx) {
                    const float* xr = x + (size_t)(b0 + lid) * TT * FF + (size_t)(i + 1) * FF + quad * 8;
                    p0 = *(const float4*)(xr);
                    p1 = *(const float4*)(xr + 4);
                    p2 = *(const float4*)(xr + 32);
                    p3 = *(const float4*)(xr + 36);
                }

                f32x4 acc[4];
#pragma unroll
                for (int g = 0; g < 4; ++g) {
                    f32x4 a = {0.f, 0.f, 0.f, 0.f};
                    a = mfma16(xf[0], wx[g][0], a);
                    a = mfma16(xf[1], wx[g][1], a);
                    a = mfma16(ah0, wh[g][0], a);
                    a = mfma16(ah1, wh[g][1], a);
                    a = mfma16(ah2, wh[g][2], a);
                    a = mfma16(ah3, wh[g][3], a);
                    acc[g] = a;
                }
#pragma unroll
                for (int r = 0; r < 4; ++r) {
                    const float zi = acc[0][r] + bias[0];
                    const float zf = acc[1][r] + bias[1];
                    const float zg = acc[2][r] + bias[2];
                    const float zo = acc[3][r] + bias[3];
                    const float ig = sigm(zi), fg = sigm(zf);
                    const float gg = fmaxf(zg, 0.f), og = sigm(zo);
                    const float cc = fg * cs[r] + ig * gg;
                    cs[r] = cc;
                    const float hv = og * fmaxf(cc, 0.f);
                    h1b[pw][quad * 4 + r][16 * w + lid] = (f16)hv;
                }
                if (hx) {
                    f16x8 f0, f1;
                    f0[0]=(f16)p0.x; f0[1]=(f16)p0.y; f0[2]=(f16)p0.z; f0[3]=(f16)p0.w;
                    f0[4]=(f16)p1.x; f0[5]=(f16)p1.y; f0[6]=(f16)p1.z; f0[7]=(f16)p1.w;
                    f1[0]=(f16)p2.x; f1[1]=(f16)p2.y; f1[2]=(f16)p2.z; f1[3]=(f16)p2.w;
                    f1[4]=(f16)p3.x; f1[5]=(f16)p3.y; f1[6]=(f16)p3.z; f1[7]=(f16)p3.w;
                    xf[0] = f0; xf[1] = f1;
                }
            }
        } else {
            if (i >= 1) {
                const int pr = (i + 1) & 1;   // h1[i-1]
                const int qr = i & 1;         // h2[i-2]
                const int qw = (i + 1) & 1;   // h2[i-1]
                f16x8 a10 = *(const f16x8*)&h1b[pr][lid][quad * 8];
                f16x8 a11 = *(const f16x8*)&h1b[pr][lid][32 + quad * 8];
                f16x8 a12 = *(const f16x8*)&h1b[pr][lid][64 + quad * 8];
                f16x8 a13 = *(const f16x8*)&h1b[pr][lid][96 + quad * 8];
                f16x8 a20 = *(const f16x8*)&h2b[qr][lid][quad * 8];
                f16x8 a21 = *(const f16x8*)&h2b[qr][lid][32 + quad * 8];

                f32x4 acc[4];
#pragma unroll
                for (int g = 0; g < 4; ++g) {
                    f32x4 a = {0.f, 0.f, 0.f, 0.f};
                    a = mfma16(a10, v2w[g][0], a);
                    a = mfma16(a11, v2w[g][1], a);
                    a = mfma16(a12, v2w[g][2], a);
                    a = mfma16(a13, v2w[g][3], a);
                    a = mfma16(a20, v2u[g][0], a);
                    a = mfma16(a21, v2u[g][1], a);
                    acc[g] = a;
                }
                const int j = w - 8;
#pragma unroll
                for (int r = 0; r < 4; ++r) {
                    const float zi = acc[0][r] + bias[0];
                    const float zf = acc[1][r] + bias[1];
                    const float zg = acc[2][r] + bias[2];
                    const float zo = acc[3][r] + bias[3];
                    const float ig = sigm(zi), fg = sigm(zf);
                    const float gg = fmaxf(zg, 0.f), og = sigm(zo);
                    const float cc = fg * cs[r] + ig * gg;
                    cs[r] = cc;
                    const float hv = og * fmaxf(cc, 0.f);
                    h2b[qw][quad * 4 + r][16 * j + lid] = (f16)hv;
                    if (i == TT) h2f[quad * 4 + r][16 * j + lid] = hv;
                }
            }
        }
        __syncthreads();
    }

    // ---------------- dense head ----------------
    for (int idx = tid; idx < 16 * D1; idx += 768) {
        const int bq = idx / D1, p = idx % D1;
        float d = bd1[p];
#pragma unroll
        for (int k = 0; k < H2; ++k) d += h2f[bq][k] * Wd1[k * D1 + p];
        dsh[bq][p] = d * Wd2[p];
    }
    __syncthreads();
    if (tid < 16) {
        float o = bd2[0];
#pragma unroll
        for (int p = 0; p < D1; ++p) o += dsh[tid][p];
        out[b0 + tid] = o;
    }
}

extern "C" void kernel_launch(void* const* d_in, const int* in_sizes, int n_in,
                              void* d_out, int out_size, void* d_ws, size_t ws_size,
                              hipStream_t stream) {
    (void)in_sizes; (void)n_in; (void)out_size; (void)d_ws; (void)ws_size;
    const float* x   = (const float*)d_in[0];
    const float* W1  = (const float*)d_in[1];
    const float* U1  = (const float*)d_in[2];
    const float* b1  = (const float*)d_in[3];
    const float* W2  = (const float*)d_in[4];
    const float* U2  = (const float*)d_in[5];
    const float* b2  = (const float*)d_in[6];
    const float* Wd1 = (const float*)d_in[7];
    const float* bd1 = (const float*)d_in[8];
    const float* Wd2 = (const float*)d_in[9];
    const float* bd2 = (const float*)d_in[10];
    float* out = (float*)d_out;

    lstm_pipe<<<dim3(32), dim3(768), 0, stream>>>(
        x, W1, U1, b1, W2, U2, b2, Wd1, bd1, Wd2, bd2, out);
}

// Round 4
// 1014.845 us; speedup vs baseline: 2.7952x; 2.7952x over previous
//
#include <hip/hip_runtime.h>

typedef _Float16 f16;
typedef _Float16 f16x4 __attribute__((ext_vector_type(4)));
typedef _Float16 f16x8 __attribute__((ext_vector_type(8)));
typedef float    f32x4 __attribute__((ext_vector_type(4)));

constexpr int TT = 512;   // timesteps
constexpr int FF = 64;    // input features
constexpr int H1 = 128;   // layer-1 hidden (512 gate cols)
constexpr int H2 = 64;    // layer-2 hidden (256 gate cols)
constexpr int D1 = 25;    // dense-1 width
constexpr int S1 = 136;   // h1 LDS row stride (f16): 16B-aligned b128, 2-way (free) banks
constexpr int S2 = 72;    // h2 LDS row stride

__device__ __forceinline__ float sigm(float z) { return 1.f / (1.f + __expf(-z)); }

__device__ __forceinline__ f32x4 mfma16(f16x8 a, f16x8 b, f32x4 c) {
    return __builtin_amdgcn_mfma_f32_16x16x32_f16(a, b, c, 0, 0, 0);
}

// pre-pass: x fp32 -> f16 (same [b][t][f] layout) so the hot loop loads
// A-fragments straight from global with no cvt and no f32 staging regs.
__global__ void cvt_x_kernel(const float* __restrict__ x, f16* __restrict__ xh) {
    const size_t i = ((size_t)blockIdx.x * blockDim.x + threadIdx.x) * 4;
    const float4 v = *(const float4*)(x + i);
    f16x4 h; h[0] = (f16)v.x; h[1] = (f16)v.y; h[2] = (f16)v.z; h[3] = (f16)v.w;
    *(f16x4*)(xh + i) = h;
}

// 32 blocks x 768 threads (12 waves, 3/SIMD). Waves 0-7: layer-1 step i
// (wave w owns gate cols 128g+16w+lid). Waves 8-11: layer-2 step i-1
// (wave 8+j owns gate cols 64g+16j+lid). Ping-pong h1/h2 LDS buffers =>
// ONE barrier/step. Weight fragments UNIFIED in wt[4][6] (96 VGPRs) so both
// roles share the same registers -- R3's spill came from two disjoint sets.
__global__ __launch_bounds__(768, 3)
void lstm_pipe2(const f16* __restrict__ xh, const float* __restrict__ W1,
                const float* __restrict__ U1, const float* __restrict__ b1,
                const float* __restrict__ W2, const float* __restrict__ U2,
                const float* __restrict__ b2, const float* __restrict__ Wd1,
                const float* __restrict__ bd1,const float* __restrict__ Wd2,
                const float* __restrict__ bd2, float* __restrict__ out)
{
    const int tid  = threadIdx.x;
    const int w    = tid >> 6;      // wave 0..11
    const int lane = tid & 63;
    const int quad = lane >> 4;     // 0..3
    const int lid  = lane & 15;     // 0..15
    const int b0   = blockIdx.x * 16;
    const bool isL1 = (w < 8);
    const int  j    = isL1 ? w : (w - 8);

    __shared__ __align__(16) f16 h1b[2][16][S1];
    __shared__ __align__(16) f16 h2b[2][16][S2];
    __shared__ float h2f[16][H2];
    __shared__ float dsh[16][D1];

    for (int i = tid; i < 2 * 16 * S1 / 2; i += 768) ((unsigned*)h1b)[i] = 0u;
    for (int i = tid; i < 2 * 16 * S2 / 2; i += 768) ((unsigned*)h2b)[i] = 0u;

    // ---- unified weight fragments: wt[g][c], B-layout n=lid, k=quad*8+e ----
    // L1 (w<8):  frag chunks 0..3 = h1 (U1 K=128), 4..5 = x (W1 K=64)
    // L2 (w>=8): frag chunks 0..3 = h1 (W2 K=128), 4..5 = h2 (U2 K=64)
    f16x8 wt[4][6];
    float bias[4];
    float cs[4] = {0.f, 0.f, 0.f, 0.f};

    if (isL1) {
#pragma unroll
        for (int g = 0; g < 4; ++g) {
            const int n = 128 * g + 16 * w + lid;
            bias[g] = b1[n];
#pragma unroll
            for (int c = 0; c < 4; ++c) {
                f16x8 f;
#pragma unroll
                for (int e = 0; e < 8; ++e)
                    f[e] = (f16)U1[(32 * c + quad * 8 + e) * 512 + n];
                wt[g][c] = f;
            }
#pragma unroll
            for (int c = 0; c < 2; ++c) {
                f16x8 f;
#pragma unroll
                for (int e = 0; e < 8; ++e)
                    f[e] = (f16)W1[(32 * c + quad * 8 + e) * 512 + n];
                wt[g][4 + c] = f;
            }
        }
    } else {
#pragma unroll
        for (int g = 0; g < 4; ++g) {
            const int n = 64 * g + 16 * j + lid;
            bias[g] = b2[n];
#pragma unroll
            for (int c = 0; c < 4; ++c) {
                f16x8 f;
#pragma unroll
                for (int e = 0; e < 8; ++e)
                    f[e] = (f16)W2[(32 * c + quad * 8 + e) * 256 + n];
                wt[g][c] = f;
            }
#pragma unroll
            for (int c = 0; c < 2; ++c) {
                f16x8 f;
#pragma unroll
                for (int e = 0; e < 8; ++e)
                    f[e] = (f16)U2[(32 * c + quad * 8 + e) * 256 + n];
                wt[g][4 + c] = f;
            }
        }
    }

    // x A-fragments, ping-pong by step parity (raw f16 loads, no cvt)
    f16x8 xfr[2][2];
    if (isL1) {
        const f16* xr = xh + ((size_t)(b0 + lid) * TT + 0) * FF + quad * 8;
        xfr[0][0] = *(const f16x8*)xr;
        xfr[0][1] = *(const f16x8*)(xr + 32);
    }
    __syncthreads();

    // ---------------- main loop: ONE barrier per iteration ----------------
#pragma unroll 2
    for (int i = 0; i <= TT; ++i) {
        const int pr = (i + 1) & 1;   // h1[i-1] buffer
        const int pw = i & 1;         // h1[i] buffer
        if (isL1) {
            if (i < TT) {
                f16x8 fr0 = *(const f16x8*)&h1b[pr][lid][quad * 8];
                f16x8 fr1 = *(const f16x8*)&h1b[pr][lid][32 + quad * 8];
                f16x8 fr2 = *(const f16x8*)&h1b[pr][lid][64 + quad * 8];
                f16x8 fr3 = *(const f16x8*)&h1b[pr][lid][96 + quad * 8];
                if (i + 1 < TT) {     // prefetch x[i+1], consumed next iter
                    const f16* xr = xh + ((size_t)(b0 + lid) * TT + (i + 1)) * FF + quad * 8;
                    xfr[(i + 1) & 1][0] = *(const f16x8*)xr;
                    xfr[(i + 1) & 1][1] = *(const f16x8*)(xr + 32);
                }
                f32x4 acc[4];
#pragma unroll
                for (int g = 0; g < 4; ++g) {
                    f32x4 a = {0.f, 0.f, 0.f, 0.f};
                    a = mfma16(fr0, wt[g][0], a);
                    a = mfma16(fr1, wt[g][1], a);
                    a = mfma16(fr2, wt[g][2], a);
                    a = mfma16(fr3, wt[g][3], a);
                    a = mfma16(xfr[i & 1][0], wt[g][4], a);
                    a = mfma16(xfr[i & 1][1], wt[g][5], a);
                    acc[g] = a;
                }
#pragma unroll
                for (int r = 0; r < 4; ++r) {
                    const float zi = acc[0][r] + bias[0];
                    const float zf = acc[1][r] + bias[1];
                    const float zg = acc[2][r] + bias[2];
                    const float zo = acc[3][r] + bias[3];
                    const float ig = sigm(zi), fg = sigm(zf);
                    const float gg = fmaxf(zg, 0.f), og = sigm(zo);
                    const float cc = fg * cs[r] + ig * gg;
                    cs[r] = cc;
                    const float hv = og * fmaxf(cc, 0.f);
                    h1b[pw][quad * 4 + r][16 * w + lid] = (f16)hv;
                }
            }
        } else {
            if (i >= 1) {
                const int qr = i & 1;         // h2[i-2]
                const int qw = (i + 1) & 1;   // h2[i-1]
                f16x8 fr0 = *(const f16x8*)&h1b[pr][lid][quad * 8];
                f16x8 fr1 = *(const f16x8*)&h1b[pr][lid][32 + quad * 8];
                f16x8 fr2 = *(const f16x8*)&h1b[pr][lid][64 + quad * 8];
                f16x8 fr3 = *(const f16x8*)&h1b[pr][lid][96 + quad * 8];
                f16x8 fr4 = *(const f16x8*)&h2b[qr][lid][quad * 8];
                f16x8 fr5 = *(const f16x8*)&h2b[qr][lid][32 + quad * 8];
                f32x4 acc[4];
#pragma unroll
                for (int g = 0; g < 4; ++g) {
                    f32x4 a = {0.f, 0.f, 0.f, 0.f};
                    a = mfma16(fr0, wt[g][0], a);
                    a = mfma16(fr1, wt[g][1], a);
                    a = mfma16(fr2, wt[g][2], a);
                    a = mfma16(fr3, wt[g][3], a);
                    a = mfma16(fr4, wt[g][4], a);
                    a = mfma16(fr5, wt[g][5], a);
                    acc[g] = a;
                }
#pragma unroll
                for (int r = 0; r < 4; ++r) {
                    const float zi = acc[0][r] + bias[0];
                    const float zf = acc[1][r] + bias[1];
                    const float zg = acc[2][r] + bias[2];
                    const float zo = acc[3][r] + bias[3];
                    const float ig = sigm(zi), fg = sigm(zf);
                    const float gg = fmaxf(zg, 0.f), og = sigm(zo);
                    const float cc = fg * cs[r] + ig * gg;
                    cs[r] = cc;
                    const float hv = og * fmaxf(cc, 0.f);
                    h2b[qw][quad * 4 + r][16 * j + lid] = (f16)hv;
                    if (i == TT) h2f[quad * 4 + r][16 * j + lid] = hv;
                }
            }
        }
        __syncthreads();
    }

    // ---------------- dense head ----------------
    for (int idx = tid; idx < 16 * D1; idx += 768) {
        const int bq = idx / D1, p = idx % D1;
        float d = bd1[p];
#pragma unroll
        for (int k = 0; k < H2; ++k) d += h2f[bq][k] * Wd1[k * D1 + p];
        dsh[bq][p] = d * Wd2[p];
    }
    __syncthreads();
    if (tid < 16) {
        float o = bd2[0];
#pragma unroll
        for (int p = 0; p < D1; ++p) o += dsh[tid][p];
        out[b0 + tid] = o;
    }
}

extern "C" void kernel_launch(void* const* d_in, const int* in_sizes, int n_in,
                              void* d_out, int out_size, void* d_ws, size_t ws_size,
                              hipStream_t stream) {
    (void)in_sizes; (void)n_in; (void)out_size; (void)ws_size;
    const float* x   = (const float*)d_in[0];
    const float* W1  = (const float*)d_in[1];
    const float* U1  = (const float*)d_in[2];
    const float* b1  = (const float*)d_in[3];
    const float* W2  = (const float*)d_in[4];
    const float* U2  = (const float*)d_in[5];
    const float* b2  = (const float*)d_in[6];
    const float* Wd1 = (const float*)d_in[7];
    const float* bd1 = (const float*)d_in[8];
    const float* Wd2 = (const float*)d_in[9];
    const float* bd2 = (const float*)d_in[10];
    float* out = (float*)d_out;
    f16*   xh  = (f16*)d_ws;    // 512*512*64 f16 = 32 MiB scratch

    const int nx = 512 * 512 * 64;
    cvt_x_kernel<<<dim3(nx / (256 * 4)), dim3(256), 0, stream>>>(x, xh);
    lstm_pipe2<<<dim3(32), dim3(768), 0, stream>>>(
        xh, W1, U1, b1, W2, U2, b2, Wd1, bd1, Wd2, bd2, out);
}

// Round 5
// 1003.590 us; speedup vs baseline: 2.8265x; 1.0112x over previous
//
#include <hip/hip_runtime.h>

typedef _Float16 f16;
typedef _Float16 f16x4 __attribute__((ext_vector_type(4)));
typedef _Float16 f16x8 __attribute__((ext_vector_type(8)));
typedef float    f32x4 __attribute__((ext_vector_type(4)));

constexpr int TT = 512;   // timesteps
constexpr int FF = 64;    // input features
constexpr int H1 = 128;   // layer-1 hidden (512 gate cols)
constexpr int H2 = 64;    // layer-2 hidden (256 gate cols)
constexpr int D1 = 25;    // dense-1 width
constexpr int S1 = 136;   // h1 LDS row stride (f16): 16B-aligned b128, 4-dword bank skew/row
constexpr int S2 = 72;    // h2 LDS row stride

__device__ __forceinline__ float sigm(float z) { return 1.f / (1.f + __expf(-z)); }

__device__ __forceinline__ f32x4 mfma16(f16x8 a, f16x8 b, f32x4 c) {
    return __builtin_amdgcn_mfma_f32_16x16x32_f16(a, b, c, 0, 0, 0);
}

// pre-pass: x fp32 -> f16 so the hot loop's x loads are raw A-fragments.
__global__ void cvt_x_kernel(const float* __restrict__ x, f16* __restrict__ xh) {
    const size_t i = ((size_t)blockIdx.x * blockDim.x + threadIdx.x) * 4;
    const float4 v = *(const float4*)(x + i);
    f16x4 h; h[0] = (f16)v.x; h[1] = (f16)v.y; h[2] = (f16)v.z; h[3] = (f16)v.w;
    *(f16x4*)(xh + i) = h;
}

// 32 blocks x 768 threads (12 waves, 3/SIMD, ~168 VGPR budget/wave).
// Waves 0-7: layer-1 step i (wave w owns gate cols 128g+16w+lid).
// Waves 8-11: layer-2 step i-1 (wave 8+j owns gate cols 64g+16j+lid).
// Ping-pong h1/h2 LDS buffers => ONE barrier/step. Unified weight array
// wt[4][6] (96 VGPRs) shared by both roles. R4's regression cause: live set
// ~172 regs overflowed into AGPRs -> v_accvgpr copies dominated VALU. This
// version trims to ~156 (no xfr ping-pong, no unroll-2) so all stays VGPR.
__global__ __launch_bounds__(768, 3)
void lstm_pipe3(const f16* __restrict__ xh, const float* __restrict__ W1,
                const float* __restrict__ U1, const float* __restrict__ b1,
                const float* __restrict__ W2, const float* __restrict__ U2,
                const float* __restrict__ b2, const float* __restrict__ Wd1,
                const float* __restrict__ bd1,const float* __restrict__ Wd2,
                const float* __restrict__ bd2, float* __restrict__ out)
{
    const int tid  = threadIdx.x;
    const int w    = tid >> 6;      // wave 0..11
    const int lane = tid & 63;
    const int quad = lane >> 4;     // 0..3
    const int lid  = lane & 15;     // 0..15
    const int b0   = blockIdx.x * 16;
    const bool isL1 = (w < 8);
    const int  j    = isL1 ? w : (w - 8);

    __shared__ __align__(16) f16 h1b[2][16][S1];
    __shared__ __align__(16) f16 h2b[2][16][S2];
    __shared__ float h2f[16][H2];
    __shared__ float dsh[16][D1];

    for (int i = tid; i < 2 * 16 * S1 / 2; i += 768) ((unsigned*)h1b)[i] = 0u;
    for (int i = tid; i < 2 * 16 * S2 / 2; i += 768) ((unsigned*)h2b)[i] = 0u;

    // ---- unified weight fragments: wt[g][c], B-layout n=lid, k=quad*8+e ----
    // L1 (w<8):  chunks 0..3 = U1 (h1 part, K=128), 4..5 = W1 (x part, K=64)
    // L2 (w>=8): chunks 0..3 = W2 (h1 part, K=128), 4..5 = U2 (h2 part, K=64)
    f16x8 wt[4][6];
    float bias[4];
    float cs[4] = {0.f, 0.f, 0.f, 0.f};

    if (isL1) {
#pragma unroll
        for (int g = 0; g < 4; ++g) {
            const int n = 128 * g + 16 * w + lid;
            bias[g] = b1[n];
#pragma unroll
            for (int c = 0; c < 4; ++c) {
                f16x8 f;
#pragma unroll
                for (int e = 0; e < 8; ++e)
                    f[e] = (f16)U1[(32 * c + quad * 8 + e) * 512 + n];
                wt[g][c] = f;
            }
#pragma unroll
            for (int c = 0; c < 2; ++c) {
                f16x8 f;
#pragma unroll
                for (int e = 0; e < 8; ++e)
                    f[e] = (f16)W1[(32 * c + quad * 8 + e) * 512 + n];
                wt[g][4 + c] = f;
            }
        }
    } else {
#pragma unroll
        for (int g = 0; g < 4; ++g) {
            const int n = 64 * g + 16 * j + lid;
            bias[g] = b2[n];
#pragma unroll
            for (int c = 0; c < 4; ++c) {
                f16x8 f;
#pragma unroll
                for (int e = 0; e < 8; ++e)
                    f[e] = (f16)W2[(32 * c + quad * 8 + e) * 256 + n];
                wt[g][c] = f;
            }
#pragma unroll
            for (int c = 0; c < 2; ++c) {
                f16x8 f;
#pragma unroll
                for (int e = 0; e < 8; ++e)
                    f[e] = (f16)U2[(32 * c + quad * 8 + e) * 256 + n];
                wt[g][4 + c] = f;
            }
        }
    }

    // single-buffer x A-fragment (prefetched one step ahead, after consumption)
    f16x8 xf0, xf1;
    if (isL1) {
        const f16* xr = xh + ((size_t)(b0 + lid) * TT + 0) * FF + quad * 8;
        xf0 = *(const f16x8*)xr;
        xf1 = *(const f16x8*)(xr + 32);
    }
    __syncthreads();

    // ---------------- main loop: ONE barrier per iteration ----------------
#pragma unroll 1
    for (int i = 0; i <= TT; ++i) {
        const int pr = (i + 1) & 1;   // h1[i-1] buffer
        const int pw = i & 1;         // h1[i] buffer
        if (isL1) {
            if (i < TT) {
                f16x8 fr0 = *(const f16x8*)&h1b[pr][lid][quad * 8];
                f16x8 fr1 = *(const f16x8*)&h1b[pr][lid][32 + quad * 8];
                f16x8 fr2 = *(const f16x8*)&h1b[pr][lid][64 + quad * 8];
                f16x8 fr3 = *(const f16x8*)&h1b[pr][lid][96 + quad * 8];
                f32x4 acc[4];
#pragma unroll
                for (int g = 0; g < 4; ++g) {
                    f32x4 a = {0.f, 0.f, 0.f, 0.f};
                    a = mfma16(fr0, wt[g][0], a);
                    a = mfma16(fr1, wt[g][1], a);
                    a = mfma16(fr2, wt[g][2], a);
                    a = mfma16(fr3, wt[g][3], a);
                    a = mfma16(xf0, wt[g][4], a);
                    a = mfma16(xf1, wt[g][5], a);
                    acc[g] = a;
                }
                // prefetch x[i+1] after xf0/xf1 consumed; lands during epilogue+barrier
                if (i + 1 < TT) {
                    const f16* xr = xh + ((size_t)(b0 + lid) * TT + (i + 1)) * FF + quad * 8;
                    xf0 = *(const f16x8*)xr;
                    xf1 = *(const f16x8*)(xr + 32);
                }
#pragma unroll
                for (int r = 0; r < 4; ++r) {
                    const float zi = acc[0][r] + bias[0];
                    const float zf = acc[1][r] + bias[1];
                    const float zg = acc[2][r] + bias[2];
                    const float zo = acc[3][r] + bias[3];
                    const float ig = sigm(zi), fg = sigm(zf);
                    const float gg = fmaxf(zg, 0.f), og = sigm(zo);
                    const float cc = fg * cs[r] + ig * gg;
                    cs[r] = cc;
                    const float hv = og * fmaxf(cc, 0.f);
                    h1b[pw][quad * 4 + r][16 * w + lid] = (f16)hv;
                }
            }
        } else {
            if (i >= 1) {
                const int qr = i & 1;         // h2[i-2]
                const int qw = (i + 1) & 1;   // h2[i-1]
                f16x8 fr0 = *(const f16x8*)&h1b[pr][lid][quad * 8];
                f16x8 fr1 = *(const f16x8*)&h1b[pr][lid][32 + quad * 8];
                f16x8 fr2 = *(const f16x8*)&h1b[pr][lid][64 + quad * 8];
                f16x8 fr3 = *(const f16x8*)&h1b[pr][lid][96 + quad * 8];
                f16x8 fr4 = *(const f16x8*)&h2b[qr][lid][quad * 8];
                f16x8 fr5 = *(const f16x8*)&h2b[qr][lid][32 + quad * 8];
                f32x4 acc[4];
#pragma unroll
                for (int g = 0; g < 4; ++g) {
                    f32x4 a = {0.f, 0.f, 0.f, 0.f};
                    a = mfma16(fr0, wt[g][0], a);
                    a = mfma16(fr1, wt[g][1], a);
                    a = mfma16(fr2, wt[g][2], a);
                    a = mfma16(fr3, wt[g][3], a);
                    a = mfma16(fr4, wt[g][4], a);
                    a = mfma16(fr5, wt[g][5], a);
                    acc[g] = a;
                }
#pragma unroll
                for (int r = 0; r < 4; ++r) {
                    const float zi = acc[0][r] + bias[0];
                    const float zf = acc[1][r] + bias[1];
                    const float zg = acc[2][r] + bias[2];
                    const float zo = acc[3][r] + bias[3];
                    const float ig = sigm(zi), fg = sigm(zf);
                    const float gg = fmaxf(zg, 0.f), og = sigm(zo);
                    const float cc = fg * cs[r] + ig * gg;
                    cs[r] = cc;
                    const float hv = og * fmaxf(cc, 0.f);
                    h2b[qw][quad * 4 + r][16 * j + lid] = (f16)hv;
                    if (i == TT) h2f[quad * 4 + r][16 * j + lid] = hv;
                }
            }
        }
        __syncthreads();
    }

    // ---------------- dense head ----------------
    for (int idx = tid; idx < 16 * D1; idx += 768) {
        const int bq = idx / D1, p = idx % D1;
        float d = bd1[p];
#pragma unroll
        for (int k = 0; k < H2; ++k) d += h2f[bq][k] * Wd1[k * D1 + p];
        dsh[bq][p] = d * Wd2[p];
    }
    __syncthreads();
    if (tid < 16) {
        float o = bd2[0];
#pragma unroll
        for (int p = 0; p < D1; ++p) o += dsh[tid][p];
        out[b0 + tid] = o;
    }
}

extern "C" void kernel_launch(void* const* d_in, const int* in_sizes, int n_in,
                              void* d_out, int out_size, void* d_ws, size_t ws_size,
                              hipStream_t stream) {
    (void)in_sizes; (void)n_in; (void)out_size; (void)ws_size;
    const float* x   = (const float*)d_in[0];
    const float* W1  = (const float*)d_in[1];
    const float* U1  = (const float*)d_in[2];
    const float* b1  = (const float*)d_in[3];
    const float* W2  = (const float*)d_in[4];
    const float* U2  = (const float*)d_in[5];
    const float* b2  = (const float*)d_in[6];
    const float* Wd1 = (const float*)d_in[7];
    const float* bd1 = (const float*)d_in[8];
    const float* Wd2 = (const float*)d_in[9];
    const float* bd2 = (const float*)d_in[10];
    float* out = (float*)d_out;
    f16*   xh  = (f16*)d_ws;    // 512*512*64 f16 = 32 MiB scratch

    const int nx = 512 * 512 * 64;
    cvt_x_kernel<<<dim3(nx / (256 * 4)), dim3(256), 0, stream>>>(x, xh);
    lstm_pipe3<<<dim3(32), dim3(768), 0, stream>>>(
        xh, W1, U1, b1, W2, U2, b2, Wd1, bd1, Wd2, bd2, out);
}

// Round 6
// 762.761 us; speedup vs baseline: 3.7190x; 1.3157x over previous
//
#include <hip/hip_runtime.h>

typedef _Float16 f16;
typedef _Float16 f16x4 __attribute__((ext_vector_type(4)));
typedef _Float16 f16x8 __attribute__((ext_vector_type(8)));
typedef float    f32x4 __attribute__((ext_vector_type(4)));

constexpr int TT = 512;   // timesteps
constexpr int FF = 64;    // input features
constexpr int H1 = 128;   // layer-1 hidden (512 gate cols)
constexpr int H2 = 64;    // layer-2 hidden (256 gate cols)
constexpr int D1 = 25;    // dense-1 width
constexpr int S1 = 136;   // h1 LDS row stride (f16): 16B-aligned, 2-way banks (free)
constexpr int S2 = 72;    // h2 LDS row stride
constexpr int XC = 8;     // x timesteps per staged LDS chunk (8*16*64 f16 = 16 KB)

__device__ __forceinline__ float sigm(float z) {
    // 4 VALU: v_mul, v_exp, v_add, v_rcp. rcp is ~1ulp — fine at our 10x margin.
    return __builtin_amdgcn_rcpf(1.f + __expf(-z));
}

__device__ __forceinline__ f32x4 mfma16(f16x8 a, f16x8 b, f32x4 c) {
    return __builtin_amdgcn_mfma_f32_16x16x32_f16(a, b, c, 0, 0, 0);
}

__device__ __forceinline__ void gl_lds16(const f16* g, f16* l) {
    __builtin_amdgcn_global_load_lds(
        (const __attribute__((address_space(1))) unsigned int*)g,
        (__attribute__((address_space(3))) unsigned int*)l, 16, 0, 0);
}

// pre-pass: x fp32 -> f16 so staging is a raw byte copy.
__global__ void cvt_x_kernel(const float* __restrict__ x, f16* __restrict__ xh) {
    const size_t i = ((size_t)blockIdx.x * blockDim.x + threadIdx.x) * 4;
    const float4 v = *(const float4*)(x + i);
    f16x4 h; h[0] = (f16)v.x; h[1] = (f16)v.y; h[2] = (f16)v.z; h[3] = (f16)v.w;
    *(f16x4*)(xh + i) = h;
}

// 32 blocks x 768 threads (12 waves, 3/SIMD). Waves 0-7: layer-1 step i
// (wave w owns gate cols 128g+16w+lid). Waves 8-11: layer-2 step i-1
// (wave 8+j owns gate cols 64g+16j+lid). Ping-pong h1/h2 LDS buffers =>
// ONE barrier/step. x double-buffered in LDS, 8 steps/chunk, staged by
// global_load_lds (no per-step vmcnt drain at the barrier). Fast sigmoid.
__global__ __launch_bounds__(768, 3)
void lstm_pipe4(const f16* __restrict__ xh, const float* __restrict__ W1,
                const float* __restrict__ U1, const float* __restrict__ b1,
                const float* __restrict__ W2, const float* __restrict__ U2,
                const float* __restrict__ b2, const float* __restrict__ Wd1,
                const float* __restrict__ bd1,const float* __restrict__ Wd2,
                const float* __restrict__ bd2, float* __restrict__ out)
{
    const int tid  = threadIdx.x;
    const int w    = tid >> 6;      // wave 0..11
    const int lane = tid & 63;
    const int quad = lane >> 4;     // 0..3
    const int lid  = lane & 15;     // 0..15
    const int b0   = blockIdx.x * 16;
    const bool isL1 = (w < 8);
    const int  j    = isL1 ? w : (w - 8);

    __shared__ __align__(16) f16 h1b[2][16][S1];
    __shared__ __align__(16) f16 h2b[2][16][S2];
    // x chunk layout: [tl(8)][fseg(8)][row(16)] of 8-f16 segments (16 B each).
    // Read at (tl, fseg=quad | 4+quad, row=lid): banks 4*lid -> 2-way, free.
    __shared__ __align__(16) f16 xlds[2][XC * 8 * 16 * 8];
    __shared__ float h2f[16][H2];
    __shared__ float dsh[16][D1];

    for (int i = tid; i < 2 * 16 * S1 / 2; i += 768) ((unsigned*)h1b)[i] = 0u;
    for (int i = tid; i < 2 * 16 * S2 / 2; i += 768) ((unsigned*)h2b)[i] = 0u;

    // stage x chunk 0 (timesteps 0..7) into xlds[0]
    for (int s = tid; s < XC * 8 * 16; s += 768) {
        const int tl = s >> 7, fs = (s >> 4) & 7, row = s & 15;
        const f16* gp = xh + ((size_t)(b0 + row) * TT + tl) * FF + fs * 8;
        gl_lds16(gp, &xlds[0][(s >> 6) * 512]);   // wave-uniform base, lane*16 implicit
    }

    // ---- unified weight fragments wt[g][c]: B-layout n=lid, k=quad*8+e ----
    // L1 (w<8):  chunks 0..3 = U1 (h1, K=128), 4..5 = W1 (x, K=64)
    // L2 (w>=8): chunks 0..3 = W2 (h1, K=128), 4..5 = U2 (h2, K=64)
    f16x8 wt[4][6];
    float bias[4];
    float cs[4] = {0.f, 0.f, 0.f, 0.f};

    if (isL1) {
#pragma unroll
        for (int g = 0; g < 4; ++g) {
            const int n = 128 * g + 16 * w + lid;
            bias[g] = b1[n];
#pragma unroll
            for (int c = 0; c < 4; ++c) {
                f16x8 f;
#pragma unroll
                for (int e = 0; e < 8; ++e)
                    f[e] = (f16)U1[(32 * c + quad * 8 + e) * 512 + n];
                wt[g][c] = f;
            }
#pragma unroll
            for (int c = 0; c < 2; ++c) {
                f16x8 f;
#pragma unroll
                for (int e = 0; e < 8; ++e)
                    f[e] = (f16)W1[(32 * c + quad * 8 + e) * 512 + n];
                wt[g][4 + c] = f;
            }
        }
    } else {
#pragma unroll
        for (int g = 0; g < 4; ++g) {
            const int n = 64 * g + 16 * j + lid;
            bias[g] = b2[n];
#pragma unroll
            for (int c = 0; c < 4; ++c) {
                f16x8 f;
#pragma unroll
                for (int e = 0; e < 8; ++e)
                    f[e] = (f16)W2[(32 * c + quad * 8 + e) * 256 + n];
                wt[g][c] = f;
            }
#pragma unroll
            for (int c = 0; c < 2; ++c) {
                f16x8 f;
#pragma unroll
                for (int e = 0; e < 8; ++e)
                    f[e] = (f16)U2[(32 * c + quad * 8 + e) * 256 + n];
                wt[g][4 + c] = f;
            }
        }
    }
    __syncthreads();   // drains staging vmcnt too

    // ---------------- main loop: ONE barrier per iteration ----------------
#pragma unroll 1
    for (int i = 0; i <= TT; ++i) {
        // stage next x chunk at chunk boundaries (drains at this step's barrier)
        if ((i & (XC - 1)) == 0 && i + XC < TT) {
            const int nc = (i >> 3) + 1;
            f16* dst = xlds[nc & 1];
            for (int s = tid; s < XC * 8 * 16; s += 768) {
                const int tl = s >> 7, fs = (s >> 4) & 7, row = s & 15;
                const f16* gp = xh + ((size_t)(b0 + row) * TT + (nc * XC + tl)) * FF + fs * 8;
                gl_lds16(gp, &dst[(s >> 6) * 512]);
            }
        }
        const int pr = (i + 1) & 1;   // h1[i-1] buffer
        const int pw = i & 1;         // h1[i] buffer
        if (isL1) {
            if (i < TT) {
                const f16* xc = &xlds[(i >> 3) & 1][(i & 7) * 1024];
                f16x8 fr0 = *(const f16x8*)&h1b[pr][lid][quad * 8];
                f16x8 fr1 = *(const f16x8*)&h1b[pr][lid][32 + quad * 8];
                f16x8 fr2 = *(const f16x8*)&h1b[pr][lid][64 + quad * 8];
                f16x8 fr3 = *(const f16x8*)&h1b[pr][lid][96 + quad * 8];
                f16x8 xf0 = *(const f16x8*)&xc[(quad * 16 + lid) * 8];
                f16x8 xf1 = *(const f16x8*)&xc[((4 + quad) * 16 + lid) * 8];
                f32x4 acc[4];
#pragma unroll
                for (int g = 0; g < 4; ++g) {
                    f32x4 a = {bias[g], bias[g], bias[g], bias[g]};
                    a = mfma16(fr0, wt[g][0], a);
                    a = mfma16(fr1, wt[g][1], a);
                    a = mfma16(fr2, wt[g][2], a);
                    a = mfma16(fr3, wt[g][3], a);
                    a = mfma16(xf0, wt[g][4], a);
                    a = mfma16(xf1, wt[g][5], a);
                    acc[g] = a;
                }
#pragma unroll
                for (int r = 0; r < 4; ++r) {
                    const float ig = sigm(acc[0][r]);
                    const float fg = sigm(acc[1][r]);
                    const float gg = fmaxf(acc[2][r], 0.f);
                    const float og = sigm(acc[3][r]);
                    const float cc = fg * cs[r] + ig * gg;
                    cs[r] = cc;
                    const float hv = og * fmaxf(cc, 0.f);
                    h1b[pw][quad * 4 + r][16 * w + lid] = (f16)hv;
                }
            }
        } else {
            if (i >= 1) {
                const int qr = i & 1;         // h2[i-2]
                const int qw = (i + 1) & 1;   // h2[i-1]
                f16x8 fr0 = *(const f16x8*)&h1b[pr][lid][quad * 8];
                f16x8 fr1 = *(const f16x8*)&h1b[pr][lid][32 + quad * 8];
                f16x8 fr2 = *(const f16x8*)&h1b[pr][lid][64 + quad * 8];
                f16x8 fr3 = *(const f16x8*)&h1b[pr][lid][96 + quad * 8];
                f16x8 fr4 = *(const f16x8*)&h2b[qr][lid][quad * 8];
                f16x8 fr5 = *(const f16x8*)&h2b[qr][lid][32 + quad * 8];
                f32x4 acc[4];
#pragma unroll
                for (int g = 0; g < 4; ++g) {
                    f32x4 a = {bias[g], bias[g], bias[g], bias[g]};
                    a = mfma16(fr0, wt[g][0], a);
                    a = mfma16(fr1, wt[g][1], a);
                    a = mfma16(fr2, wt[g][2], a);
                    a = mfma16(fr3, wt[g][3], a);
                    a = mfma16(fr4, wt[g][4], a);
                    a = mfma16(fr5, wt[g][5], a);
                    acc[g] = a;
                }
#pragma unroll
                for (int r = 0; r < 4; ++r) {
                    const float ig = sigm(acc[0][r]);
                    const float fg = sigm(acc[1][r]);
                    const float gg = fmaxf(acc[2][r], 0.f);
                    const float og = sigm(acc[3][r]);
                    const float cc = fg * cs[r] + ig * gg;
                    cs[r] = cc;
                    const float hv = og * fmaxf(cc, 0.f);
                    h2b[qw][quad * 4 + r][16 * j + lid] = (f16)hv;
                    if (i == TT) h2f[quad * 4 + r][16 * j + lid] = hv;
                }
            }
        }
        __syncthreads();
    }

    // ---------------- dense head ----------------
    for (int idx = tid; idx < 16 * D1; idx += 768) {
        const int bq = idx / D1, p = idx % D1;
        float d = bd1[p];
#pragma unroll
        for (int k = 0; k < H2; ++k) d += h2f[bq][k] * Wd1[k * D1 + p];
        dsh[bq][p] = d * Wd2[p];
    }
    __syncthreads();
    if (tid < 16) {
        float o = bd2[0];
#pragma unroll
        for (int p = 0; p < D1; ++p) o += dsh[tid][p];
        out[b0 + tid] = o;
    }
}

extern "C" void kernel_launch(void* const* d_in, const int* in_sizes, int n_in,
                              void* d_out, int out_size, void* d_ws, size_t ws_size,
                              hipStream_t stream) {
    (void)in_sizes; (void)n_in; (void)out_size; (void)ws_size;
    const float* x   = (const float*)d_in[0];
    const float* W1  = (const float*)d_in[1];
    const float* U1  = (const float*)d_in[2];
    const float* b1  = (const float*)d_in[3];
    const float* W2  = (const float*)d_in[4];
    const float* U2  = (const float*)d_in[5];
    const float* b2  = (const float*)d_in[6];
    const float* Wd1 = (const float*)d_in[7];
    const float* bd1 = (const float*)d_in[8];
    const float* Wd2 = (const float*)d_in[9];
    const float* bd2 = (const float*)d_in[10];
    float* out = (float*)d_out;
    f16*   xh  = (f16*)d_ws;    // 512*512*64 f16 = 32 MiB scratch

    const int nx = 512 * 512 * 64;
    cvt_x_kernel<<<dim3(nx / (256 * 4)), dim3(256), 0, stream>>>(x, xh);
    lstm_pipe4<<<dim3(32), dim3(768), 0, stream>>>(
        xh, W1, U1, b1, W2, U2, b2, Wd1, bd1, Wd2, bd2, out);
}

// Round 7
// 749.350 us; speedup vs baseline: 3.7855x; 1.0179x over previous
//
#include <hip/hip_runtime.h>
#include <type_traits>

typedef _Float16 f16;
typedef _Float16 f16x4 __attribute__((ext_vector_type(4)));
typedef _Float16 f16x8 __attribute__((ext_vector_type(8)));
typedef float    f32x4 __attribute__((ext_vector_type(4)));

constexpr int TT = 512;   // timesteps
constexpr int FF = 64;    // input features
constexpr int H1 = 128;   // layer-1 hidden (512 gate cols)
constexpr int H2 = 64;    // layer-2 hidden (256 gate cols)
constexpr int D1 = 25;    // dense-1 width
constexpr int S1 = 136;   // h1 LDS row stride (f16)
constexpr int S2 = 72;    // h2 LDS row stride
constexpr int XC = 8;     // x timesteps per staged LDS chunk
constexpr float L2E = 1.44269504088896f;

// z pre-scaled by log2(e) at weight-load time: sigmoid = rcp(1 + 2^-z).
__device__ __forceinline__ float sigm2(float z) {
    return __builtin_amdgcn_rcpf(1.f + __builtin_amdgcn_exp2f(-z));
}

__device__ __forceinline__ f32x4 mfma16(f16x8 a, f16x8 b, f32x4 c) {
    return __builtin_amdgcn_mfma_f32_16x16x32_f16(a, b, c, 0, 0, 0);
}

__device__ __forceinline__ void gl_lds16(const f16* g, f16* l) {
    __builtin_amdgcn_global_load_lds(
        (const __attribute__((address_space(1))) unsigned int*)g,
        (__attribute__((address_space(3))) unsigned int*)l, 16, 0, 0);
}

// pre-pass: x fp32 -> f16 so staging is a raw byte copy.
__global__ void cvt_x_kernel(const float* __restrict__ x, f16* __restrict__ xh) {
    const size_t i = ((size_t)blockIdx.x * blockDim.x + threadIdx.x) * 4;
    const float4 v = *(const float4*)(x + i);
    f16x4 h; h[0] = (f16)v.x; h[1] = (f16)v.y; h[2] = (f16)v.z; h[3] = (f16)v.w;
    *(f16x4*)(xh + i) = h;
}

// 32 blocks x 768 threads (12 waves, 3/SIMD). Waves 0-7: layer-1 step i.
// Waves 8-11: layer-2 step i-1 (1-step software pipeline). ONE barrier/step.
// R7: explicit x2 unroll w/ compile-time ping-pong parity (LDS offsets become
// immediates), bias-splat as MFMA C operand (no acc init), i/f/o weights
// pre-scaled by log2e (sigmoid = rcp(1+exp2(-z)), one fewer VALU/sigmoid).
__global__ __launch_bounds__(768, 3)
void lstm_pipe5(const f16* __restrict__ xh, const float* __restrict__ W1,
                const float* __restrict__ U1, const float* __restrict__ b1,
                const float* __restrict__ W2, const float* __restrict__ U2,
                const float* __restrict__ b2, const float* __restrict__ Wd1,
                const float* __restrict__ bd1,const float* __restrict__ Wd2,
                const float* __restrict__ bd2, float* __restrict__ out)
{
    const int tid  = threadIdx.x;
    const int w    = tid >> 6;      // wave 0..11
    const int lane = tid & 63;
    const int quad = lane >> 4;     // 0..3
    const int lid  = lane & 15;     // 0..15
    const int b0   = blockIdx.x * 16;
    const bool isL1 = (w < 8);
    const int  j    = isL1 ? w : (w - 8);

    __shared__ __align__(16) f16 h1b[2][16][S1];
    __shared__ __align__(16) f16 h2b[2][16][S2];
    // x chunk layout: [tl(8)][fseg(8)][row(16)] of 8-f16 (16 B) segments.
    __shared__ __align__(16) f16 xlds[2][XC * 8 * 16 * 8];
    __shared__ float h2f[16][H2];
    __shared__ float dsh[16][D1];

    for (int i = tid; i < 2 * 16 * S1 / 2; i += 768) ((unsigned*)h1b)[i] = 0u;
    for (int i = tid; i < 2 * 16 * S2 / 2; i += 768) ((unsigned*)h2b)[i] = 0u;

    // stage x chunk 0 (timesteps 0..7) into xlds[0]
    for (int s = tid; s < XC * 8 * 16; s += 768) {
        const int tl = s >> 7, fs = (s >> 4) & 7, row = s & 15;
        const f16* gp = xh + ((size_t)(b0 + row) * TT + tl) * FF + fs * 8;
        gl_lds16(gp, &xlds[0][(s >> 6) * 512]);
    }

    // ---- unified weight fragments wt[g][c]: B-layout n=lid, k=quad*8+e ----
    // gates 0,1,3 (i,f,o) pre-scaled by log2e; gate 2 (candidate, relu) raw.
    // L1 (w<8):  chunks 0..3 = U1 (h1, K=128), 4..5 = W1 (x, K=64)
    // L2 (w>=8): chunks 0..3 = W2 (h1, K=128), 4..5 = U2 (h2, K=64)
    f16x8 wt[4][6];
    f32x4 bsp[4];                       // bias splat (C operand of first MFMA)
    float cs[4] = {0.f, 0.f, 0.f, 0.f};

    if (isL1) {
#pragma unroll
        for (int g = 0; g < 4; ++g) {
            const float sc = (g == 2) ? 1.f : L2E;
            const int n = 128 * g + 16 * w + lid;
            const float bb = b1[n] * sc;
            bsp[g][0] = bb; bsp[g][1] = bb; bsp[g][2] = bb; bsp[g][3] = bb;
#pragma unroll
            for (int c = 0; c < 4; ++c) {
                f16x8 f;
#pragma unroll
                for (int e = 0; e < 8; ++e)
                    f[e] = (f16)(U1[(32 * c + quad * 8 + e) * 512 + n] * sc);
                wt[g][c] = f;
            }
#pragma unroll
            for (int c = 0; c < 2; ++c) {
                f16x8 f;
#pragma unroll
                for (int e = 0; e < 8; ++e)
                    f[e] = (f16)(W1[(32 * c + quad * 8 + e) * 512 + n] * sc);
                wt[g][4 + c] = f;
            }
        }
    } else {
#pragma unroll
        for (int g = 0; g < 4; ++g) {
            const float sc = (g == 2) ? 1.f : L2E;
            const int n = 64 * g + 16 * j + lid;
            const float bb = b2[n] * sc;
            bsp[g][0] = bb; bsp[g][1] = bb; bsp[g][2] = bb; bsp[g][3] = bb;
#pragma unroll
            for (int c = 0; c < 4; ++c) {
                f16x8 f;
#pragma unroll
                for (int e = 0; e < 8; ++e)
                    f[e] = (f16)(W2[(32 * c + quad * 8 + e) * 256 + n] * sc);
                wt[g][c] = f;
            }
#pragma unroll
            for (int c = 0; c < 2; ++c) {
                f16x8 f;
#pragma unroll
                for (int e = 0; e < 8; ++e)
                    f[e] = (f16)(U2[(32 * c + quad * 8 + e) * 256 + n] * sc);
                wt[g][4 + c] = f;
            }
        }
    }
    __syncthreads();   // also drains staging vmcnt

    // one pipeline step; PAR = i&1 known at compile time => LDS immediates
    auto step = [&](auto parc, int i) {
        constexpr int PAR = decltype(parc)::value;
        constexpr int PR = PAR ^ 1;   // h1[i-1] buffer
        constexpr int PW = PAR;       // h1[i]   buffer
        constexpr int QR = PAR;       // h2[i-2] buffer
        constexpr int QW = PAR ^ 1;   // h2[i-1] buffer
        if (isL1) {
            const f16* xc = &xlds[(i >> 3) & 1][(i & 7) * 1024];
            f16x8 fr0 = *(const f16x8*)&h1b[PR][lid][quad * 8];
            f16x8 fr1 = *(const f16x8*)&h1b[PR][lid][32 + quad * 8];
            f16x8 fr2 = *(const f16x8*)&h1b[PR][lid][64 + quad * 8];
            f16x8 fr3 = *(const f16x8*)&h1b[PR][lid][96 + quad * 8];
            f16x8 xf0 = *(const f16x8*)&xc[(quad * 16 + lid) * 8];
            f16x8 xf1 = *(const f16x8*)&xc[((4 + quad) * 16 + lid) * 8];
            f32x4 acc[4];
#pragma unroll
            for (int g = 0; g < 4; ++g) {
                f32x4 a = mfma16(fr0, wt[g][0], bsp[g]);
                a = mfma16(fr1, wt[g][1], a);
                a = mfma16(fr2, wt[g][2], a);
                a = mfma16(fr3, wt[g][3], a);
                a = mfma16(xf0, wt[g][4], a);
                a = mfma16(xf1, wt[g][5], a);
                acc[g] = a;
            }
#pragma unroll
            for (int r = 0; r < 4; ++r) {
                const float ig = sigm2(acc[0][r]);
                const float fg = sigm2(acc[1][r]);
                const float gg = fmaxf(acc[2][r], 0.f);
                const float og = sigm2(acc[3][r]);
                const float cc = fg * cs[r] + ig * gg;
                cs[r] = cc;
                const float hv = og * fmaxf(cc, 0.f);
                h1b[PW][quad * 4 + r][16 * w + lid] = (f16)hv;
            }
        } else {
            if (i >= 1) {
                f16x8 fr0 = *(const f16x8*)&h1b[PR][lid][quad * 8];
                f16x8 fr1 = *(const f16x8*)&h1b[PR][lid][32 + quad * 8];
                f16x8 fr2 = *(const f16x8*)&h1b[PR][lid][64 + quad * 8];
                f16x8 fr3 = *(const f16x8*)&h1b[PR][lid][96 + quad * 8];
                f16x8 fr4 = *(const f16x8*)&h2b[QR][lid][quad * 8];
                f16x8 fr5 = *(const f16x8*)&h2b[QR][lid][32 + quad * 8];
                f32x4 acc[4];
#pragma unroll
                for (int g = 0; g < 4; ++g) {
                    f32x4 a = mfma16(fr0, wt[g][0], bsp[g]);
                    a = mfma16(fr1, wt[g][1], a);
                    a = mfma16(fr2, wt[g][2], a);
                    a = mfma16(fr3, wt[g][3], a);
                    a = mfma16(fr4, wt[g][4], a);
                    a = mfma16(fr5, wt[g][5], a);
                    acc[g] = a;
                }
#pragma unroll
                for (int r = 0; r < 4; ++r) {
                    const float ig = sigm2(acc[0][r]);
                    const float fg = sigm2(acc[1][r]);
                    const float gg = fmaxf(acc[2][r], 0.f);
                    const float og = sigm2(acc[3][r]);
                    const float cc = fg * cs[r] + ig * gg;
                    cs[r] = cc;
                    const float hv = og * fmaxf(cc, 0.f);
                    h2b[QW][quad * 4 + r][16 * j + lid] = (f16)hv;
                }
            }
        }
    };

    // ---------------- main loop, unrolled x2: ONE barrier per step ----------------
    for (int ii = 0; ii < TT; ii += 2) {
        if ((ii & (XC - 1)) == 0 && ii + XC < TT) {
            const int nc = (ii >> 3) + 1;
            f16* dst = xlds[nc & 1];
            for (int s = tid; s < XC * 8 * 16; s += 768) {
                const int tl = s >> 7, fs = (s >> 4) & 7, row = s & 15;
                const f16* gp = xh + ((size_t)(b0 + row) * TT + (nc * XC + tl)) * FF + fs * 8;
                gl_lds16(gp, &dst[(s >> 6) * 512]);
            }
        }
        step(std::integral_constant<int, 0>{}, ii);
        __syncthreads();
        step(std::integral_constant<int, 1>{}, ii + 1);
        __syncthreads();
    }

    // final pipeline step i=TT (even): L2 consumes h1[TT-1]; also export h2 f32
    if (!isL1) {
        f16x8 fr0 = *(const f16x8*)&h1b[1][lid][quad * 8];
        f16x8 fr1 = *(const f16x8*)&h1b[1][lid][32 + quad * 8];
        f16x8 fr2 = *(const f16x8*)&h1b[1][lid][64 + quad * 8];
        f16x8 fr3 = *(const f16x8*)&h1b[1][lid][96 + quad * 8];
        f16x8 fr4 = *(const f16x8*)&h2b[0][lid][quad * 8];
        f16x8 fr5 = *(const f16x8*)&h2b[0][lid][32 + quad * 8];
        f32x4 acc[4];
#pragma unroll
        for (int g = 0; g < 4; ++g) {
            f32x4 a = mfma16(fr0, wt[g][0], bsp[g]);
            a = mfma16(fr1, wt[g][1], a);
            a = mfma16(fr2, wt[g][2], a);
            a = mfma16(fr3, wt[g][3], a);
            a = mfma16(fr4, wt[g][4], a);
            a = mfma16(fr5, wt[g][5], a);
            acc[g] = a;
        }
#pragma unroll
        for (int r = 0; r < 4; ++r) {
            const float ig = sigm2(acc[0][r]);
            const float fg = sigm2(acc[1][r]);
            const float gg = fmaxf(acc[2][r], 0.f);
            const float og = sigm2(acc[3][r]);
            const float cc = fg * cs[r] + ig * gg;
            const float hv = og * fmaxf(cc, 0.f);
            h2f[quad * 4 + r][16 * j + lid] = hv;
        }
    }
    __syncthreads();

    // ---------------- dense head ----------------
    for (int idx = tid; idx < 16 * D1; idx += 768) {
        const int bq = idx / D1, p = idx % D1;
        float d = bd1[p];
#pragma unroll
        for (int k = 0; k < H2; ++k) d += h2f[bq][k] * Wd1[k * D1 + p];
        dsh[bq][p] = d * Wd2[p];
    }
    __syncthreads();
    if (tid < 16) {
        float o = bd2[0];
#pragma unroll
        for (int p = 0; p < D1; ++p) o += dsh[tid][p];
        out[b0 + tid] = o;
    }
}

extern "C" void kernel_launch(void* const* d_in, const int* in_sizes, int n_in,
                              void* d_out, int out_size, void* d_ws, size_t ws_size,
                              hipStream_t stream) {
    (void)in_sizes; (void)n_in; (void)out_size; (void)ws_size;
    const float* x   = (const float*)d_in[0];
    const float* W1  = (const float*)d_in[1];
    const float* U1  = (const float*)d_in[2];
    const float* b1  = (const float*)d_in[3];
    const float* W2  = (const float*)d_in[4];
    const float* U2  = (const float*)d_in[5];
    const float* b2  = (const float*)d_in[6];
    const float* Wd1 = (const float*)d_in[7];
    const float* bd1 = (const float*)d_in[8];
    const float* Wd2 = (const float*)d_in[9];
    const float* bd2 = (const float*)d_in[10];
    float* out = (float*)d_out;
    f16*   xh  = (f16*)d_ws;    // 512*512*64 f16 = 32 MiB scratch

    const int nx = 512 * 512 * 64;
    cvt_x_kernel<<<dim3(nx / (256 * 4)), dim3(256), 0, stream>>>(x, xh);
    lstm_pipe5<<<dim3(32), dim3(768), 0, stream>>>(
        xh, W1, U1, b1, W2, U2, b2, Wd1, bd1, Wd2, bd2, out);
}